// Round 17
// baseline (377.712 us; speedup 1.0000x reference)
//
#include <hip/hip_runtime.h>
#include <math.h>

#define TOKS   32768
#define NSEQ   8192
#define BATCH  4
#define DIMD   1024
#define LHID   512
#define HHID   4096
#define NHEAVY 1024

typedef __attribute__((ext_vector_type(8))) short bf16x8;
typedef __attribute__((ext_vector_type(4))) float f32x4;
typedef __attribute__((ext_vector_type(8))) unsigned short u16x8;
typedef __attribute__((ext_vector_type(4))) unsigned short u16x4;

__device__ __forceinline__ unsigned short bf16rne(float f) {
    unsigned u = __float_as_uint(f);
    return (unsigned short)((u + 0x7FFFu + ((u >> 16) & 1u)) >> 16);
}
__device__ __forceinline__ float gelu_f(float v) {
    return 0.5f * v * (1.0f + erff(v * 0.7071067811865476f));
}
__device__ __forceinline__ void gload_lds16(const unsigned short* g, unsigned short* l) {
#if defined(__HIP_DEVICE_COMPILE__)
    __builtin_amdgcn_global_load_lds((const __attribute__((address_space(1))) void*)g,
                                     (__attribute__((address_space(3))) void*)l,
                                     16, 0, 0);
#endif
}

// ---- transpose body: W[K][N] f32 -> WT[N][K] bf16, optional per-k row scale ----
__device__ __forceinline__ void transpose_body(const float* W, unsigned short* WT,
                                               int K, int N, int n0, int k0,
                                               const float* grow) {
    __shared__ float ts[64][65];
    int t = threadIdx.x;
    int kk = t >> 2, nc = (t & 3) * 16;
    float gs = grow ? grow[k0 + kk] : 1.0f;
    const float4* src = (const float4*)(W + (size_t)(k0 + kk) * N + n0 + nc);
#pragma unroll
    for (int j = 0; j < 4; j++) {
        float4 v = src[j];
        ts[kk][nc + 4 * j + 0] = v.x * gs;
        ts[kk][nc + 4 * j + 1] = v.y * gs;
        ts[kk][nc + 4 * j + 2] = v.z * gs;
        ts[kk][nc + 4 * j + 3] = v.w * gs;
    }
    __syncthreads();
    int nn = t >> 2, kc = (t & 3) * 16;
    unsigned short o[16];
#pragma unroll
    for (int j = 0; j < 16; j++) o[j] = bf16rne(ts[kc + j][nn]);
    unsigned short* dst = WT + (size_t)(n0 + nn) * K + k0 + kc;
    *(u16x8*)(dst)     = *(u16x8*)(o);
    *(u16x8*)(dst + 8) = *(u16x8*)(o + 8);
}

// ---- fused pass 1: [0,8192) xcast rows (s, invr, xc=bf16(x)); [8192,10496) transposes ----
__global__ __launch_bounds__(256) void k_pre(const float* __restrict__ x,
                                             const float* __restrict__ rt,
                                             const float* __restrict__ gl,
                                             const float* __restrict__ gh,
                                             const float* w1l, unsigned short* w1lT,
                                             const float* w2l, unsigned short* w2lT,
                                             const float* w1h, unsigned short* w1hT,
                                             const float* w2h, unsigned short* w2hT,
                                             float* __restrict__ s,
                                             float* __restrict__ invr,
                                             unsigned short* __restrict__ xc) {
    int b = (int)blockIdx.x;
    if (b < 8192) {
        int wid = threadIdx.x >> 6, lane = threadIdx.x & 63;
        int row = b * 4 + wid;
        const float4* xr  = (const float4*)(x + (size_t)row * DIMD);
        const float4* rt4 = (const float4*)rt;
        float4 v[4];
        float dot = 0.f, ss = 0.f;
#pragma unroll
        for (int i = 0; i < 4; i++) {
            v[i] = xr[lane + 64 * i];
            float4 r = rt4[lane + 64 * i];
            dot += v[i].x * r.x + v[i].y * r.y + v[i].z * r.z + v[i].w * r.w;
            ss  += v[i].x * v[i].x + v[i].y * v[i].y + v[i].z * v[i].z + v[i].w * v[i].w;
        }
#pragma unroll
        for (int o = 32; o > 0; o >>= 1) {
            dot += __shfl_xor(dot, o);
            ss  += __shfl_xor(ss, o);
        }
        if (lane == 0) {
            s[row] = dot;
            invr[row] = 32.0f / fmaxf(sqrtf(ss), 1e-12f);
        }
#pragma unroll
        for (int i = 0; i < 4; i++) {
            u16x4 o;
            o[0] = bf16rne(v[i].x); o[1] = bf16rne(v[i].y);
            o[2] = bf16rne(v[i].z); o[3] = bf16rne(v[i].w);
            *(u16x4*)(xc + (size_t)row * DIMD + (lane + 64 * i) * 4) = o;
        }
    } else {
        int w = b - 8192;
        if (w < 128)       { int i = w;        transpose_body(w1l, w1lT, DIMD, LHID, (i % 8) * 64,  (i / 8) * 64, gl); }
        else if (w < 256)  { int i = w - 128;  transpose_body(w2l, w2lT, LHID, DIMD, (i % 16) * 64, (i / 16) * 64, nullptr); }
        else if (w < 1280) { int i = w - 256;  transpose_body(w1h, w1hT, DIMD, HHID, (i % 64) * 64, (i / 64) * 64, gh); }
        else               { int i = w - 1280; transpose_body(w2h, w2hT, HHID, DIMD, (i % 16) * 64, (i / 16) * 64, nullptr); }
    }
}

// ---- separate pass 1 (fallback) ----
__global__ __launch_bounds__(256) void k_rowstats(const float* __restrict__ x,
                                                  const float* __restrict__ rt,
                                                  float* __restrict__ s,
                                                  float* __restrict__ invr) {
    int wid = threadIdx.x >> 6, lane = threadIdx.x & 63;
    int row = blockIdx.x * 4 + wid;
    const float4* xr  = (const float4*)(x + (size_t)row * DIMD);
    const float4* rt4 = (const float4*)rt;
    float dot = 0.f, ss = 0.f;
#pragma unroll
    for (int i = 0; i < 4; i++) {
        float4 v = xr[lane + 64 * i];
        float4 r = rt4[lane + 64 * i];
        dot += v.x * r.x + v.y * r.y + v.z * r.z + v.w * r.w;
        ss  += v.x * v.x + v.y * v.y + v.z * v.z + v.w * v.w;
    }
#pragma unroll
    for (int o = 32; o > 0; o >>= 1) {
        dot += __shfl_down(dot, o);
        ss  += __shfl_down(ss, o);
    }
    if (lane == 0) {
        s[row] = dot;
        invr[row] = 32.0f / fmaxf(sqrtf(ss), 1e-12f);
    }
}

// ---- fused routing + selection ----
__global__ __launch_bounds__(1024) void k_routesel(const float* __restrict__ s_g,
                                                   int* __restrict__ rowmap) {
    int b = blockIdx.x, tid = threadIdx.x;
    int lane = tid & 63, wid = tid >> 6;
    __shared__ float red[2][16];
    __shared__ int wsum[16];
    __shared__ int ws2[16];
    __shared__ int PC[2];
    __shared__ int slot;
    __shared__ unsigned long long kk_[NSEQ];
    const float* sb = s_g + b * NSEQ;
    float sv[8];
    float smax = -3.4e38f;
#pragma unroll
    for (int i = 0; i < 8; i++) { sv[i] = sb[tid + 1024 * i]; smax = fmaxf(smax, sv[i]); }
#pragma unroll
    for (int o = 32; o > 0; o >>= 1) smax = fmaxf(smax, __shfl_xor(smax, o));
    if (lane == 0) red[0][wid] = smax;
    __syncthreads();
    float smaxAll = -3.4e38f;
    for (int w = 0; w < 16; w++) smaxAll = fmaxf(smaxAll, red[0][w]);
    __syncthreads();

    const float cst = 0.1f * logf(8.0f);
    float a = 0.0f;
    for (int it = 0; it < 50; it++) {
        float tau = -a;
        float M = fminf(smaxAll, tau);
        float p = 0.0f;
#pragma unroll
        for (int i = 0; i < 8; i++) p += expf((fminf(sv[i], tau) - M) * 10.0f);
#pragma unroll
        for (int o = 32; o > 0; o >>= 1) p += __shfl_xor(p, o);
        if (lane == 0) red[it & 1][wid] = p;
        __syncthreads();
        float S = 0.0f;
        for (int w = 0; w < 16; w++) S += red[it & 1][w];
        a = cst - M - 0.1f * logf(S);
        __syncthreads();
    }
    float sc[8];
    int p = 0, c1 = 0;
#pragma unroll
    for (int i = 0; i < 8; i++) {
        sc[i] = expf(fminf(sv[i] + a, 0.0f) * 10.0f);
        p  += (sc[i] > 0.0f) ? 1 : 0;
        c1 += (sc[i] == 1.0f) ? 1 : 0;
    }
    {
        int pp = p, cc = c1;
#pragma unroll
        for (int o = 32; o > 0; o >>= 1) {
            pp += __shfl_xor(pp, o);
            cc += __shfl_xor(cc, o);
        }
        if (lane == 0) { wsum[wid] = pp; ws2[wid] = cc; }
        __syncthreads();
        if (tid == 0) {
            int sp = 0, sC = 0;
            for (int w = 0; w < 16; w++) { sp += wsum[w]; sC += ws2[w]; }
            PC[0] = sp; PC[1] = sC;
        }
        __syncthreads();
    }
    int P = PC[0], C1 = PC[1];
    __syncthreads();

    if (C1 >= NHEAVY) {
        __shared__ unsigned char fl[NSEQ];
#pragma unroll
        for (int i = 0; i < 8; i++) fl[tid + 1024 * i] = (sc[i] == 1.0f) ? 1 : 0;
        __syncthreads();
        int zc = 0;
        unsigned char f[8];
#pragma unroll
        for (int j = 0; j < 8; j++) { f[j] = fl[tid * 8 + j]; zc += f[j]; }
        int inc = zc;
        for (int o = 1; o < 64; o <<= 1) {
            int t = __shfl_up(inc, o);
            if (lane >= o) inc += t;
        }
        if (lane == 63) wsum[wid] = inc;
        __syncthreads();
        if (tid == 0) {
            int acc = 0;
            for (int w = 0; w < 16; w++) { int t = wsum[w]; wsum[w] = acc; acc += t; }
        }
        __syncthreads();
        int rank = wsum[wid] + (inc - zc);
#pragma unroll
        for (int j = 0; j < 8; j++) {
            if (f[j]) {
                if (rank < NHEAVY) rowmap[b * NHEAVY + rank] = b * NSEQ + tid * 8 + j;
                rank++;
            }
        }
    } else if (P <= NHEAVY) {
        __shared__ unsigned char fl[NSEQ];
#pragma unroll
        for (int i = 0; i < 8; i++) fl[tid + 1024 * i] = (sc[i] > 0.0f) ? 1 : 0;
        __syncthreads();
        unsigned char pos[8]; int zc = 0;
#pragma unroll
        for (int j = 0; j < 8; j++) { pos[j] = fl[tid * 8 + j]; zc += pos[j] ? 0 : 1; }
        int inc = zc;
        for (int o = 1; o < 64; o <<= 1) {
            int t = __shfl_up(inc, o);
            if (lane >= o) inc += t;
        }
        if (lane == 63) wsum[wid] = inc;
        if (tid == 0) slot = 0;
        __syncthreads();
        if (tid == 0) {
            int acc = 0;
            for (int w = 0; w < 16; w++) { int t = wsum[w]; wsum[w] = acc; acc += t; }
        }
        __syncthreads();
        int zr = wsum[wid] + (inc - zc);
        int Z = NHEAVY - P;
#pragma unroll
        for (int j = 0; j < 8; j++) {
            int n = tid * 8 + j;
            bool sel;
            if (pos[j]) sel = true;
            else { sel = (zr < Z); zr += 1; }
            if (sel) {
                int sl = atomicAdd(&slot, 1);
                rowmap[b * NHEAVY + sl] = b * NSEQ + n;
            }
        }
    } else {
#pragma unroll
        for (int i = 0; i < 8; i++) {
            int n = tid + 1024 * i;
            kk_[n] = ((unsigned long long)__float_as_uint(sc[i]) << 32)
                   | (unsigned long long)(0xFFFFFFFFu - (unsigned)n);
        }
        __syncthreads();
        for (int k = 2; k <= NSEQ; k <<= 1) {
            for (int j = k >> 1; j > 0; j >>= 1) {
                for (int i = tid; i < NSEQ; i += 1024) {
                    int ixj = i ^ j;
                    if (ixj > i) {
                        unsigned long long u = kk_[i], v = kk_[ixj];
                        bool dirDesc = ((i & k) == 0);
                        if (dirDesc ? (u < v) : (u > v)) { kk_[i] = v; kk_[ixj] = u; }
                    }
                }
                __syncthreads();
            }
        }
        if (tid < NHEAVY) {
            unsigned idx = 0xFFFFFFFFu - (unsigned)(kk_[tid] & 0xFFFFFFFFull);
            rowmap[b * NHEAVY + tid] = b * NSEQ + (int)idx;
        }
    }
}

// ---- legacy route/select (fallback path only) ----
__global__ __launch_bounds__(1024) void k_route(const float* __restrict__ s_g,
                                                unsigned long long* __restrict__ keys,
                                                int* __restrict__ pcount,
                                                int* __restrict__ c1cnt) {
    int b = blockIdx.x, tid = threadIdx.x;
    int lane = tid & 63, wid = tid >> 6;
    const float* sb = s_g + b * NSEQ;
    float sv[8];
    float smax = -3.4e38f;
#pragma unroll
    for (int i = 0; i < 8; i++) { sv[i] = sb[tid + 1024 * i]; smax = fmaxf(smax, sv[i]); }
    __shared__ float red[2][16];
#pragma unroll
    for (int o = 32; o > 0; o >>= 1) smax = fmaxf(smax, __shfl_xor(smax, o));
    if (lane == 0) red[0][wid] = smax;
    __syncthreads();
    float smaxAll = -3.4e38f;
    for (int w = 0; w < 16; w++) smaxAll = fmaxf(smaxAll, red[0][w]);
    __syncthreads();
    const float cst = 0.1f * logf(8.0f);
    float a = 0.0f;
    for (int it = 0; it < 50; it++) {
        float tau = -a;
        float M = fminf(smaxAll, tau);
        float p = 0.0f;
#pragma unroll
        for (int i = 0; i < 8; i++) p += expf((fminf(sv[i], tau) - M) * 10.0f);
#pragma unroll
        for (int o = 32; o > 0; o >>= 1) p += __shfl_xor(p, o);
        if (lane == 0) red[it & 1][wid] = p;
        __syncthreads();
        float S = 0.0f;
        for (int w = 0; w < 16; w++) S += red[it & 1][w];
        a = cst - M - 0.1f * logf(S);
    }
    int p = 0, c1 = 0;
#pragma unroll
    for (int i = 0; i < 8; i++) {
        float sc = expf(fminf(sv[i] + a, 0.0f) * 10.0f);
        int n = tid + 1024 * i;
        keys[b * NSEQ + n] = ((unsigned long long)__float_as_uint(sc) << 32)
                           | (unsigned long long)(0xFFFFFFFFu - (unsigned)n);
        p  += (sc > 0.0f) ? 1 : 0;
        c1 += (sc == 1.0f) ? 1 : 0;
    }
#pragma unroll
    for (int o = 32; o > 0; o >>= 1) {
        p  += __shfl_xor(p, o);
        c1 += __shfl_xor(c1, o);
    }
    if (lane == 0) { atomicAdd(&pcount[b], p); atomicAdd(&c1cnt[b], c1); }
}

__global__ __launch_bounds__(1024) void k_select(const unsigned long long* __restrict__ keys,
                                                 const int* __restrict__ pcount,
                                                 const int* __restrict__ c1cnt,
                                                 int* __restrict__ rowmap) {
    int b = blockIdx.x, tid = threadIdx.x;
    int lane = tid & 63, wid = tid >> 6;
    __shared__ int wsum[16];
    __shared__ int slot;
    __shared__ unsigned long long kk_[NSEQ];
    int P = pcount[b], C1 = c1cnt[b];
    if (C1 >= NHEAVY) {
        bool f[8]; int zc = 0;
#pragma unroll
        for (int j = 0; j < 8; j++) {
            unsigned hi = (unsigned)(keys[b * NSEQ + tid * 8 + j] >> 32);
            f[j] = (hi == 0x3F800000u);
            zc += f[j] ? 1 : 0;
        }
        int inc = zc;
        for (int o = 1; o < 64; o <<= 1) {
            int t = __shfl_up(inc, o);
            if (lane >= o) inc += t;
        }
        if (lane == 63) wsum[wid] = inc;
        __syncthreads();
        if (tid == 0) {
            int acc = 0;
            for (int w = 0; w < 16; w++) { int t = wsum[w]; wsum[w] = acc; acc += t; }
        }
        __syncthreads();
        int rank = wsum[wid] + (inc - zc);
#pragma unroll
        for (int j = 0; j < 8; j++) {
            if (f[j]) {
                if (rank < NHEAVY) rowmap[b * NHEAVY + rank] = b * NSEQ + tid * 8 + j;
                rank++;
            }
        }
    } else if (P <= NHEAVY) {
        bool pos[8]; int zc = 0;
#pragma unroll
        for (int j = 0; j < 8; j++) {
            unsigned sbits = (unsigned)(keys[b * NSEQ + tid * 8 + j] >> 32);
            pos[j] = (sbits != 0u);
            zc += pos[j] ? 0 : 1;
        }
        int inc = zc;
        for (int o = 1; o < 64; o <<= 1) {
            int t = __shfl_up(inc, o);
            if (lane >= o) inc += t;
        }
        if (lane == 63) wsum[wid] = inc;
        if (tid == 0) slot = 0;
        __syncthreads();
        if (tid == 0) {
            int acc = 0;
            for (int w = 0; w < 16; w++) { int t = wsum[w]; wsum[w] = acc; acc += t; }
        }
        __syncthreads();
        int zr = wsum[wid] + (inc - zc);
        int Z = NHEAVY - P;
#pragma unroll
        for (int j = 0; j < 8; j++) {
            int n = tid * 8 + j;
            bool sel;
            if (pos[j]) sel = true;
            else { sel = (zr < Z); zr += 1; }
            if (sel) {
                int sl = atomicAdd(&slot, 1);
                rowmap[b * NHEAVY + sl] = b * NSEQ + n;
            }
        }
    } else {
        for (int i = tid; i < NSEQ; i += 1024) kk_[i] = keys[b * NSEQ + i];
        __syncthreads();
        for (int k = 2; k <= NSEQ; k <<= 1) {
            for (int j = k >> 1; j > 0; j >>= 1) {
                for (int i = tid; i < NSEQ; i += 1024) {
                    int ixj = i ^ j;
                    if (ixj > i) {
                        unsigned long long u = kk_[i], v = kk_[ixj];
                        bool dirDesc = ((i & k) == 0);
                        if (dirDesc ? (u < v) : (u > v)) { kk_[i] = v; kk_[ixj] = u; }
                    }
                }
                __syncthreads();
            }
        }
        unsigned idx = 0xFFFFFFFFu - (unsigned)(kk_[tid] & 0xFFFFFFFFull);
        rowmap[b * NHEAVY + tid] = b * NSEQ + (int)idx;
    }
}

__global__ __launch_bounds__(256) void k_transpose(const float* __restrict__ W,
                                                   unsigned short* __restrict__ WT,
                                                   int K, int N) {
    transpose_body(W, WT, K, N, blockIdx.x * 64, blockIdx.y * 64, nullptr);
}

// ---- prescale (fallback path) ----
__global__ __launch_bounds__(256) void k_prescale(const float* __restrict__ x,
                                                  const float* __restrict__ invr,
                                                  const float* __restrict__ gamma,
                                                  const int* __restrict__ rowmap,
                                                  unsigned short* __restrict__ xo,
                                                  int row_ofs) {
    int t = threadIdx.x;
    int i = blockIdx.x * 2 + (t >> 7);
    int c = (t & 127) * 8;
    int src = rowmap ? rowmap[i] : (row_ofs + i);
    float iv = invr[src];
    const float4* px = (const float4*)(x + (size_t)src * DIMD + c);
    const float4* pg = (const float4*)(gamma + c);
    float4 v0 = px[0], v1 = px[1];
    float4 g0 = pg[0], g1 = pg[1];
    unsigned short o[8];
    o[0] = bf16rne(v0.x * iv * g0.x); o[1] = bf16rne(v0.y * iv * g0.y);
    o[2] = bf16rne(v0.z * iv * g0.z); o[3] = bf16rne(v0.w * iv * g0.w);
    o[4] = bf16rne(v1.x * iv * g1.x); o[5] = bf16rne(v1.y * iv * g1.y);
    o[6] = bf16rne(v1.z * iv * g1.z); o[7] = bf16rne(v1.w * iv * g1.w);
    *(u16x8*)(xo + (size_t)i * DIMD + c) = *(u16x8*)o;
}

// ---- scatter-add: out[rowmap[i]][*] += rb[i][*]  (rows unique, no atomics) ----
__global__ __launch_bounds__(256) void k_scatter(const float* __restrict__ rb,
                                                 const int* __restrict__ rowmap,
                                                 float* __restrict__ out) {
    int i = blockIdx.x;
    int c = threadIdx.x * 4;
    int g = rowmap[i];
    float4 v = *(const float4*)(rb + (size_t)i * DIMD + c);
    float* p = out + (size_t)g * DIMD + c;
    float4 o = *(const float4*)p;
    o.x += v.x; o.y += v.y; o.z += v.z; o.w += v.w;
    *(float4*)p = o;
}

// ---- 128x128 bf16 MFMA GEMM body (R9-proven loop; VGPR 64, 0 conflicts) ----
// EPI 0: bf16 gelu(acc+bias)
// EPI 1: f32 C[m_ofs+row] = acc+bias
// EPI 2: f32 C[rowmap[m_ofs+row]] += acc+bias      [fallback heavy-G2]
// EPI 3: atomicAdd(C[rowmap?rowmap[row]:row], acc + (bz==0?bias:0))  [split-K]
// EPI 5: bf16 gelu(acc*invr[row]+bias)             [light-G1]
// EPI 6: GATHER A via rowmap; bf16 gelu(acc*invr[rowmap[row]]+bias)  [heavy-G1]
struct GArg {
    const unsigned short* A; const unsigned short* BT; const float* bias;
    void* C; const int* rowmap; const float* invr;
    int K, kslice, m_ofs, ldc, nx, ny;
};

template<int EPI>
__device__ __forceinline__ void gemm_body(const GArg ga, int w, int nwg,
                                          unsigned short* As, unsigned short* Bs) {
    int tid = threadIdx.x;
    int q = nwg >> 3, r = nwg & 7;
    int xcd = w & 7, sub = w >> 3;
    int id = (xcd < r ? xcd * (q + 1) : r * (q + 1) + (xcd - r) * q) + sub;
    int bx = id % ga.nx;
    int t2 = id / ga.nx;
    int by = t2 % ga.ny;
    int bz = t2 / ga.ny;

    int m0 = by * 128, n0 = bx * 128;
    int kbeg = bz * ga.kslice, kend = kbeg + ga.kslice;
    int K = ga.K;
    int lane = tid & 63, wid = tid >> 6;
    int wm = wid >> 1, wn = wid & 1;
    int lc = lane & 15, lr = lane >> 4;

    int srow = lane >> 3;
    int sslot = (lane & 7) ^ srow;
    const unsigned short* paB = ga.BT + (size_t)(n0 + srow) * K + sslot * 8;
    const unsigned short* paA;
    int growq[4];
    if constexpr (EPI == 6) {
#pragma unroll
        for (int qq = 0; qq < 4; qq++)
            growq[qq] = ga.rowmap[m0 + (wid * 4 + qq) * 8 + srow];
        paA = ga.A + sslot * 8;
    } else {
        paA = ga.A + (size_t)(m0 + srow) * K + sslot * 8;
    }

    f32x4 acc[4][4];
#pragma unroll
    for (int i = 0; i < 4; i++)
#pragma unroll
        for (int j = 0; j < 4; j++) acc[i][j] = (f32x4){0.f, 0.f, 0.f, 0.f};

    for (int k0 = kbeg; k0 < kend; k0 += 64) {
        if (k0 != kbeg) __syncthreads();
#pragma unroll
        for (int qq = 0; qq < 4; qq++) {
            int rb_ = (wid * 4 + qq) * 8;
            if constexpr (EPI == 6)
                gload_lds16(paA + (size_t)growq[qq] * K + k0, &As[rb_ * 64]);
            else
                gload_lds16(paA + (size_t)rb_ * K + k0, &As[rb_ * 64]);
            gload_lds16(paB + (size_t)rb_ * K + k0, &Bs[rb_ * 64]);
        }
        __syncthreads();
#pragma unroll
        for (int ks = 0; ks < 2; ks++) {
            bf16x8 af[4], bfr[4];
#pragma unroll
            for (int f = 0; f < 4; f++) {
                int rowA = wm * 64 + f * 16 + lc;
                int rowB = wn * 64 + f * 16 + lc;
                int sw = ((ks * 4 + lr) ^ (lc & 7)) << 4;
                af[f]  = *(const bf16x8*)((const char*)As + rowA * 128 + sw);
                bfr[f] = *(const bf16x8*)((const char*)Bs + rowB * 128 + sw);
            }
#pragma unroll
            for (int fm = 0; fm < 4; fm++)
#pragma unroll
                for (int fn = 0; fn < 4; fn++)
                    acc[fm][fn] = __builtin_amdgcn_mfma_f32_16x16x32_bf16(
                        af[fm], bfr[fn], acc[fm][fn], 0, 0, 0);
        }
    }

    float bcol[4];
#pragma unroll
    for (int fn = 0; fn < 4; fn++) {
        float bb = ga.bias[n0 + wn * 64 + fn * 16 + lc];
        if constexpr (EPI == 3) { if (bz != 0) bb = 0.0f; }
        bcol[fn] = bb;
    }
#pragma unroll
    for (int fm = 0; fm < 4; fm++) {
        int rowb = m0 + wm * 64 + fm * 16 + lr * 4;
#pragma unroll
        for (int fn = 0; fn < 4; fn++) {
            int col = n0 + wn * 64 + fn * 16 + lc;
            f32x4 v = acc[fm][fn];
#pragma unroll
            for (int rr = 0; rr < 4; rr++) {
                if constexpr (EPI == 0) {
                    float val = v[rr] + bcol[fn];
                    ((unsigned short*)ga.C)[(size_t)(rowb + rr) * ga.ldc + col] =
                        bf16rne(gelu_f(val));
                } else if constexpr (EPI == 1) {
                    ((float*)ga.C)[(size_t)(ga.m_ofs + rowb + rr) * ga.ldc + col] =
                        v[rr] + bcol[fn];
                } else if constexpr (EPI == 2) {
                    int g = ga.rowmap[ga.m_ofs + rowb + rr];
                    float* p = (float*)ga.C + (size_t)g * ga.ldc + col;
                    *p = *p + v[rr] + bcol[fn];
                } else if constexpr (EPI == 3) {
                    int g = ga.rowmap ? ga.rowmap[rowb + rr] : (rowb + rr);
                    atomicAdd((float*)ga.C + (size_t)g * ga.ldc + col, v[rr] + bcol[fn]);
                } else if constexpr (EPI == 5) {
                    float val = v[rr] * ga.invr[rowb + rr] + bcol[fn];
                    ((unsigned short*)ga.C)[(size_t)(rowb + rr) * ga.ldc + col] =
                        bf16rne(gelu_f(val));
                } else {  // EPI == 6
                    int g = ga.rowmap[rowb + rr];
                    float val = v[rr] * ga.invr[g] + bcol[fn];
                    ((unsigned short*)ga.C)[(size_t)(rowb + rr) * ga.ldc + col] =
                        bf16rne(gelu_f(val));
                }
            }
        }
    }
}

// (256,4) is the measured optimum for this body: VGPR 64, no spill.
// (256,5) twice measured to squeeze VGPR -> scratch spill (R10, R15). Do not raise.
template<int EPI>
__global__ __launch_bounds__(256, 4) void k_mfma(GArg ga) {
    __shared__ unsigned short sm[2][128 * 64];
    gemm_body<EPI>(ga, (int)blockIdx.x, (int)gridDim.x, sm[0], sm[1]);
}

template<int EA, int EB>
__global__ __launch_bounds__(256, 4) void k_mfma2(GArg a, GArg b, int nwgA) {
    __shared__ unsigned short sm[2][128 * 64];
    int w = (int)blockIdx.x;
    if (w < nwgA) gemm_body<EA>(a, w, nwgA, sm[0], sm[1]);
    else          gemm_body<EB>(b, w - nwgA, (int)gridDim.x - nwgA, sm[0], sm[1]);
}

extern "C" void kernel_launch(void* const* d_in, const int* in_sizes, int n_in,
                              void* d_out, int out_size, void* d_ws, size_t ws_size,
                              hipStream_t stream) {
    const float* x   = (const float*)d_in[0];
    const float* rt  = (const float*)d_in[1];
    const float* gl  = (const float*)d_in[2];
    const float* w1l = (const float*)d_in[3];
    const float* b1l = (const float*)d_in[4];
    const float* w2l = (const float*)d_in[5];
    const float* b2l = (const float*)d_in[6];
    const float* gh  = (const float*)d_in[7];
    const float* w1h = (const float*)d_in[8];
    const float* b1h = (const float*)d_in[9];
    const float* w2h = (const float*)d_in[10];
    const float* b2h = (const float*)d_in[11];
    float* out = (float*)d_out;

    char* ws = (char*)d_ws;
    float* s    = (float*)(ws);
    float* invr = (float*)(ws + 131072);
    unsigned long long* keys = (unsigned long long*)(ws + 262144);
    int* rowmap = (int*)(ws + 524288);
    int* pcount = (int*)(ws + 540672);
    int* c1cnt  = pcount + 4;
    size_t off = 1u << 20;
    unsigned short* w1lT = (unsigned short*)(ws + off); off += (size_t)LHID * DIMD * 2;
    unsigned short* w2lT = (unsigned short*)(ws + off); off += (size_t)DIMD * LHID * 2;
    unsigned short* w1hT = (unsigned short*)(ws + off); off += (size_t)HHID * DIMD * 2;
    unsigned short* w2hT = (unsigned short*)(ws + off); off += (size_t)DIMD * HHID * 2;
    unsigned short* xhg  = (unsigned short*)(ws + off); off += (size_t)BATCH * NHEAVY * DIMD * 2;
    char* un = ws + off;
    size_t U = ws_size > off ? ws_size - off : 0;

    const size_t XL_B = (size_t)TOKS * DIMD * 2;           // 64 MiB
    const size_t HL_B = (size_t)TOKS * LHID * 2;           // 32 MiB
    const size_t HH_B = (size_t)BATCH * NHEAVY * HHID * 2; // 32 MiB
    bool big = (U >= XL_B + HL_B + HH_B);

    const long MH = (long)BATCH * NHEAVY;   // 4096

    if (big) {
        unsigned short* xc = (unsigned short*)un;
        unsigned short* hl = (unsigned short*)(un + XL_B);
        unsigned short* hh = (unsigned short*)(un + XL_B + HL_B);
        float* rb = (float*)un;                            // aliases xc (dead after G1)

        // D1: xcast (s, invr, xc) || all 4 weight transposes (gamma folded into w1*)
        k_pre<<<8192 + 2304, 256, 0, stream>>>(x, rt, gl, gh,
                                               w1l, w1lT, w2l, w2lT,
                                               w1h, w1hT, w2h, w2hT,
                                               s, invr, xc);
        // D2: routing + selection
        k_routesel<<<BATCH, 1024, 0, stream>>>(s, rowmap);

        // D3 MEGA-G1: heavy-G1 gather (1024) || light-G1 (1024), both K=1024
        GArg hg1{xc, w1hT, b1h, hh, rowmap, invr, DIMD, DIMD, 0, HHID, HHID / 128, (int)MH / 128};
        GArg lg1{xc, w1lT, b1l, hl, nullptr, invr, DIMD, DIMD, 0, LHID, LHID / 128, TOKS / 128};
        k_mfma2<6, 5><<<2048, 256, 0, stream>>>(hg1, lg1, 1024);

        // rb zero (aliases xc, dead after G1)
        hipMemsetAsync(rb, 0, (size_t)MH * DIMD * 4, stream);

        // D4 MEGA-G2: heavy-G2 SPLIT-K x4 (1024 blocks, 16 steps) -> rb atomically
        //           || light-G2 (2048 blocks, 8 steps) -> out.  Uniform depth kills
        //           the 1-block/CU heavy tail that pinned mega-G2 at ~146 us.
        GArg hg2{hh, w2hT, b2h, rb,  nullptr, nullptr, HHID, HHID / 4, 0, DIMD, DIMD / 128, (int)MH / 128};
        GArg lg2{hl, w2lT, b2l, out, nullptr, nullptr, LHID, LHID, 0, DIMD, DIMD / 128, TOKS / 128};
        k_mfma2<3, 1><<<3072, 256, 0, stream>>>(hg2, lg2, 1024);

        // D5: scatter heavy rows into out
        k_scatter<<<(unsigned)MH, 256, 0, stream>>>(rb, rowmap, out);
    } else {
        // fallback: chunked path (small workspace)
        hipMemsetAsync(pcount, 0, 32, stream);
        k_rowstats<<<TOKS / 4, 256, 0, stream>>>(x, rt, s, invr);
        k_route<<<BATCH, 1024, 0, stream>>>(s, keys, pcount, c1cnt);
        k_select<<<BATCH, 1024, 0, stream>>>(keys, pcount, c1cnt, rowmap);

        k_transpose<<<dim3(LHID / 64, DIMD / 64), 256, 0, stream>>>(w1l, w1lT, DIMD, LHID);
        k_transpose<<<dim3(DIMD / 64, LHID / 64), 256, 0, stream>>>(w2l, w2lT, LHID, DIMD);
        k_transpose<<<dim3(HHID / 64, DIMD / 64), 256, 0, stream>>>(w1h, w1hT, DIMD, HHID);
        k_transpose<<<dim3(DIMD / 64, HHID / 64), 256, 0, stream>>>(w2h, w2hT, HHID, DIMD);

        long Rl = (long)(U / 3072);
        Rl -= Rl % 128; if (Rl < 128) Rl = 128; if (Rl > TOKS) Rl = TOKS;
        unsigned short* xl = (unsigned short*)un;
        unsigned short* hl = (unsigned short*)(un + (size_t)Rl * DIMD * 2);
        for (long mo = 0; mo < TOKS; mo += Rl) {
            long R = TOKS - mo < Rl ? TOKS - mo : Rl;
            k_prescale<<<(unsigned)(R / 2), 256, 0, stream>>>(x, invr, gl, nullptr, xl, (int)mo);
            GArg a1{xl, w1lT, b1l, hl, nullptr, nullptr, DIMD, DIMD, 0, LHID, LHID / 128, (int)(R / 128)};
            k_mfma<0><<<(LHID / 128) * (unsigned)(R / 128), 256, 0, stream>>>(a1);
            GArg a2{hl, w2lT, b2l, out, nullptr, nullptr, LHID, LHID, (int)mo, DIMD, DIMD / 128, (int)(R / 128)};
            k_mfma<1><<<(DIMD / 128) * (unsigned)(R / 128), 256, 0, stream>>>(a2);
        }

        k_prescale<<<(unsigned)(MH / 2), 256, 0, stream>>>(x, invr, gh, rowmap, xhg, 0);
        long Rh = (long)(U / ((size_t)HHID * 2));
        Rh -= Rh % 128; if (Rh < 128) Rh = 128; if (Rh > MH) Rh = MH;
        unsigned short* hh = (unsigned short*)un;
        for (long mo = 0; mo < MH; mo += Rh) {
            long R = MH - mo < Rh ? MH - mo : Rh;
            GArg b1{xhg + (size_t)mo * DIMD, w1hT, b1h, hh, nullptr, nullptr, DIMD, DIMD, 0, HHID,
                    HHID / 128, (int)(R / 128)};
            k_mfma<0><<<(HHID / 128) * (unsigned)(R / 128), 256, 0, stream>>>(b1);
            GArg b2{hh, w2hT, b2h, out, rowmap, nullptr, HHID, HHID, (int)mo, DIMD,
                    DIMD / 128, (int)(R / 128)};
            k_mfma<2><<<(DIMD / 128) * (unsigned)(R / 128), 256, 0, stream>>>(b2);
        }
    }
}

// Round 18
// 331.712 us; speedup vs baseline: 1.1387x; 1.1387x over previous
//
#include <hip/hip_runtime.h>
#include <math.h>

#define TOKS   32768
#define NSEQ   8192
#define BATCH  4
#define DIMD   1024
#define LHID   512
#define HHID   4096
#define NHEAVY 1024

typedef __attribute__((ext_vector_type(8))) short bf16x8;
typedef __attribute__((ext_vector_type(4))) float f32x4;
typedef __attribute__((ext_vector_type(8))) unsigned short u16x8;
typedef __attribute__((ext_vector_type(4))) unsigned short u16x4;

__device__ __forceinline__ unsigned short bf16rne(float f) {
    unsigned u = __float_as_uint(f);
    return (unsigned short)((u + 0x7FFFu + ((u >> 16) & 1u)) >> 16);
}
__device__ __forceinline__ float gelu_f(float v) {
    return 0.5f * v * (1.0f + erff(v * 0.7071067811865476f));
}
__device__ __forceinline__ void gload_lds16(const unsigned short* g, unsigned short* l) {
#if defined(__HIP_DEVICE_COMPILE__)
    __builtin_amdgcn_global_load_lds((const __attribute__((address_space(1))) void*)g,
                                     (__attribute__((address_space(3))) void*)l,
                                     16, 0, 0);
#endif
}

// ---- transpose body: W[K][N] f32 -> WT[N][K] bf16, optional per-k row scale ----
__device__ __forceinline__ void transpose_body(const float* W, unsigned short* WT,
                                               int K, int N, int n0, int k0,
                                               const float* grow) {
    __shared__ float ts[64][65];
    int t = threadIdx.x;
    int kk = t >> 2, nc = (t & 3) * 16;
    float gs = grow ? grow[k0 + kk] : 1.0f;
    const float4* src = (const float4*)(W + (size_t)(k0 + kk) * N + n0 + nc);
#pragma unroll
    for (int j = 0; j < 4; j++) {
        float4 v = src[j];
        ts[kk][nc + 4 * j + 0] = v.x * gs;
        ts[kk][nc + 4 * j + 1] = v.y * gs;
        ts[kk][nc + 4 * j + 2] = v.z * gs;
        ts[kk][nc + 4 * j + 3] = v.w * gs;
    }
    __syncthreads();
    int nn = t >> 2, kc = (t & 3) * 16;
    unsigned short o[16];
#pragma unroll
    for (int j = 0; j < 16; j++) o[j] = bf16rne(ts[kc + j][nn]);
    unsigned short* dst = WT + (size_t)(n0 + nn) * K + k0 + kc;
    *(u16x8*)(dst)     = *(u16x8*)(o);
    *(u16x8*)(dst + 8) = *(u16x8*)(o + 8);
}

// ---- fused pass 1: [0,8192) xcast rows (s, invr, xc=bf16(x)); [8192,10496) transposes ----
__global__ __launch_bounds__(256) void k_pre(const float* __restrict__ x,
                                             const float* __restrict__ rt,
                                             const float* __restrict__ gl,
                                             const float* __restrict__ gh,
                                             const float* w1l, unsigned short* w1lT,
                                             const float* w2l, unsigned short* w2lT,
                                             const float* w1h, unsigned short* w1hT,
                                             const float* w2h, unsigned short* w2hT,
                                             float* __restrict__ s,
                                             float* __restrict__ invr,
                                             unsigned short* __restrict__ xc) {
    int b = (int)blockIdx.x;
    if (b < 8192) {
        int wid = threadIdx.x >> 6, lane = threadIdx.x & 63;
        int row = b * 4 + wid;
        const float4* xr  = (const float4*)(x + (size_t)row * DIMD);
        const float4* rt4 = (const float4*)rt;
        float4 v[4];
        float dot = 0.f, ss = 0.f;
#pragma unroll
        for (int i = 0; i < 4; i++) {
            v[i] = xr[lane + 64 * i];
            float4 r = rt4[lane + 64 * i];
            dot += v[i].x * r.x + v[i].y * r.y + v[i].z * r.z + v[i].w * r.w;
            ss  += v[i].x * v[i].x + v[i].y * v[i].y + v[i].z * v[i].z + v[i].w * v[i].w;
        }
#pragma unroll
        for (int o = 32; o > 0; o >>= 1) {
            dot += __shfl_xor(dot, o);
            ss  += __shfl_xor(ss, o);
        }
        if (lane == 0) {
            s[row] = dot;
            invr[row] = 32.0f / fmaxf(sqrtf(ss), 1e-12f);
        }
#pragma unroll
        for (int i = 0; i < 4; i++) {
            u16x4 o;
            o[0] = bf16rne(v[i].x); o[1] = bf16rne(v[i].y);
            o[2] = bf16rne(v[i].z); o[3] = bf16rne(v[i].w);
            *(u16x4*)(xc + (size_t)row * DIMD + (lane + 64 * i) * 4) = o;
        }
    } else {
        int w = b - 8192;
        if (w < 128)       { int i = w;        transpose_body(w1l, w1lT, DIMD, LHID, (i % 8) * 64,  (i / 8) * 64, gl); }
        else if (w < 256)  { int i = w - 128;  transpose_body(w2l, w2lT, LHID, DIMD, (i % 16) * 64, (i / 16) * 64, nullptr); }
        else if (w < 1280) { int i = w - 256;  transpose_body(w1h, w1hT, DIMD, HHID, (i % 64) * 64, (i / 64) * 64, gh); }
        else               { int i = w - 1280; transpose_body(w2h, w2hT, HHID, DIMD, (i % 16) * 64, (i / 16) * 64, nullptr); }
    }
}

// ---- separate pass 1 (fallback) ----
__global__ __launch_bounds__(256) void k_rowstats(const float* __restrict__ x,
                                                  const float* __restrict__ rt,
                                                  float* __restrict__ s,
                                                  float* __restrict__ invr) {
    int wid = threadIdx.x >> 6, lane = threadIdx.x & 63;
    int row = blockIdx.x * 4 + wid;
    const float4* xr  = (const float4*)(x + (size_t)row * DIMD);
    const float4* rt4 = (const float4*)rt;
    float dot = 0.f, ss = 0.f;
#pragma unroll
    for (int i = 0; i < 4; i++) {
        float4 v = xr[lane + 64 * i];
        float4 r = rt4[lane + 64 * i];
        dot += v.x * r.x + v.y * r.y + v.z * r.z + v.w * r.w;
        ss  += v.x * v.x + v.y * v.y + v.z * v.z + v.w * v.w;
    }
#pragma unroll
    for (int o = 32; o > 0; o >>= 1) {
        dot += __shfl_down(dot, o);
        ss  += __shfl_down(ss, o);
    }
    if (lane == 0) {
        s[row] = dot;
        invr[row] = 32.0f / fmaxf(sqrtf(ss), 1e-12f);
    }
}

// ---- fused routing + selection ----
__global__ __launch_bounds__(1024) void k_routesel(const float* __restrict__ s_g,
                                                   int* __restrict__ rowmap) {
    int b = blockIdx.x, tid = threadIdx.x;
    int lane = tid & 63, wid = tid >> 6;
    __shared__ float red[2][16];
    __shared__ int wsum[16];
    __shared__ int ws2[16];
    __shared__ int PC[2];
    __shared__ int slot;
    __shared__ unsigned long long kk_[NSEQ];
    const float* sb = s_g + b * NSEQ;
    float sv[8];
    float smax = -3.4e38f;
#pragma unroll
    for (int i = 0; i < 8; i++) { sv[i] = sb[tid + 1024 * i]; smax = fmaxf(smax, sv[i]); }
#pragma unroll
    for (int o = 32; o > 0; o >>= 1) smax = fmaxf(smax, __shfl_xor(smax, o));
    if (lane == 0) red[0][wid] = smax;
    __syncthreads();
    float smaxAll = -3.4e38f;
    for (int w = 0; w < 16; w++) smaxAll = fmaxf(smaxAll, red[0][w]);
    __syncthreads();

    const float cst = 0.1f * logf(8.0f);
    float a = 0.0f;
    for (int it = 0; it < 50; it++) {
        float tau = -a;
        float M = fminf(smaxAll, tau);
        float p = 0.0f;
#pragma unroll
        for (int i = 0; i < 8; i++) p += expf((fminf(sv[i], tau) - M) * 10.0f);
#pragma unroll
        for (int o = 32; o > 0; o >>= 1) p += __shfl_xor(p, o);
        if (lane == 0) red[it & 1][wid] = p;
        __syncthreads();
        float S = 0.0f;
        for (int w = 0; w < 16; w++) S += red[it & 1][w];
        a = cst - M - 0.1f * logf(S);
        __syncthreads();
    }
    float sc[8];
    int p = 0, c1 = 0;
#pragma unroll
    for (int i = 0; i < 8; i++) {
        sc[i] = expf(fminf(sv[i] + a, 0.0f) * 10.0f);
        p  += (sc[i] > 0.0f) ? 1 : 0;
        c1 += (sc[i] == 1.0f) ? 1 : 0;
    }
    {
        int pp = p, cc = c1;
#pragma unroll
        for (int o = 32; o > 0; o >>= 1) {
            pp += __shfl_xor(pp, o);
            cc += __shfl_xor(cc, o);
        }
        if (lane == 0) { wsum[wid] = pp; ws2[wid] = cc; }
        __syncthreads();
        if (tid == 0) {
            int sp = 0, sC = 0;
            for (int w = 0; w < 16; w++) { sp += wsum[w]; sC += ws2[w]; }
            PC[0] = sp; PC[1] = sC;
        }
        __syncthreads();
    }
    int P = PC[0], C1 = PC[1];
    __syncthreads();

    if (C1 >= NHEAVY) {
        __shared__ unsigned char fl[NSEQ];
#pragma unroll
        for (int i = 0; i < 8; i++) fl[tid + 1024 * i] = (sc[i] == 1.0f) ? 1 : 0;
        __syncthreads();
        int zc = 0;
        unsigned char f[8];
#pragma unroll
        for (int j = 0; j < 8; j++) { f[j] = fl[tid * 8 + j]; zc += f[j]; }
        int inc = zc;
        for (int o = 1; o < 64; o <<= 1) {
            int t = __shfl_up(inc, o);
            if (lane >= o) inc += t;
        }
        if (lane == 63) wsum[wid] = inc;
        __syncthreads();
        if (tid == 0) {
            int acc = 0;
            for (int w = 0; w < 16; w++) { int t = wsum[w]; wsum[w] = acc; acc += t; }
        }
        __syncthreads();
        int rank = wsum[wid] + (inc - zc);
#pragma unroll
        for (int j = 0; j < 8; j++) {
            if (f[j]) {
                if (rank < NHEAVY) rowmap[b * NHEAVY + rank] = b * NSEQ + tid * 8 + j;
                rank++;
            }
        }
    } else if (P <= NHEAVY) {
        __shared__ unsigned char fl[NSEQ];
#pragma unroll
        for (int i = 0; i < 8; i++) fl[tid + 1024 * i] = (sc[i] > 0.0f) ? 1 : 0;
        __syncthreads();
        unsigned char pos[8]; int zc = 0;
#pragma unroll
        for (int j = 0; j < 8; j++) { pos[j] = fl[tid * 8 + j]; zc += pos[j] ? 0 : 1; }
        int inc = zc;
        for (int o = 1; o < 64; o <<= 1) {
            int t = __shfl_up(inc, o);
            if (lane >= o) inc += t;
        }
        if (lane == 63) wsum[wid] = inc;
        if (tid == 0) slot = 0;
        __syncthreads();
        if (tid == 0) {
            int acc = 0;
            for (int w = 0; w < 16; w++) { int t = wsum[w]; wsum[w] = acc; acc += t; }
        }
        __syncthreads();
        int zr = wsum[wid] + (inc - zc);
        int Z = NHEAVY - P;
#pragma unroll
        for (int j = 0; j < 8; j++) {
            int n = tid * 8 + j;
            bool sel;
            if (pos[j]) sel = true;
            else { sel = (zr < Z); zr += 1; }
            if (sel) {
                int sl = atomicAdd(&slot, 1);
                rowmap[b * NHEAVY + sl] = b * NSEQ + n;
            }
        }
    } else {
#pragma unroll
        for (int i = 0; i < 8; i++) {
            int n = tid + 1024 * i;
            kk_[n] = ((unsigned long long)__float_as_uint(sc[i]) << 32)
                   | (unsigned long long)(0xFFFFFFFFu - (unsigned)n);
        }
        __syncthreads();
        for (int k = 2; k <= NSEQ; k <<= 1) {
            for (int j = k >> 1; j > 0; j >>= 1) {
                for (int i = tid; i < NSEQ; i += 1024) {
                    int ixj = i ^ j;
                    if (ixj > i) {
                        unsigned long long u = kk_[i], v = kk_[ixj];
                        bool dirDesc = ((i & k) == 0);
                        if (dirDesc ? (u < v) : (u > v)) { kk_[i] = v; kk_[ixj] = u; }
                    }
                }
                __syncthreads();
            }
        }
        if (tid < NHEAVY) {
            unsigned idx = 0xFFFFFFFFu - (unsigned)(kk_[tid] & 0xFFFFFFFFull);
            rowmap[b * NHEAVY + tid] = b * NSEQ + (int)idx;
        }
    }
}

// ---- legacy route/select (fallback path only) ----
__global__ __launch_bounds__(1024) void k_route(const float* __restrict__ s_g,
                                                unsigned long long* __restrict__ keys,
                                                int* __restrict__ pcount,
                                                int* __restrict__ c1cnt) {
    int b = blockIdx.x, tid = threadIdx.x;
    int lane = tid & 63, wid = tid >> 6;
    const float* sb = s_g + b * NSEQ;
    float sv[8];
    float smax = -3.4e38f;
#pragma unroll
    for (int i = 0; i < 8; i++) { sv[i] = sb[tid + 1024 * i]; smax = fmaxf(smax, sv[i]); }
    __shared__ float red[2][16];
#pragma unroll
    for (int o = 32; o > 0; o >>= 1) smax = fmaxf(smax, __shfl_xor(smax, o));
    if (lane == 0) red[0][wid] = smax;
    __syncthreads();
    float smaxAll = -3.4e38f;
    for (int w = 0; w < 16; w++) smaxAll = fmaxf(smaxAll, red[0][w]);
    __syncthreads();
    const float cst = 0.1f * logf(8.0f);
    float a = 0.0f;
    for (int it = 0; it < 50; it++) {
        float tau = -a;
        float M = fminf(smaxAll, tau);
        float p = 0.0f;
#pragma unroll
        for (int i = 0; i < 8; i++) p += expf((fminf(sv[i], tau) - M) * 10.0f);
#pragma unroll
        for (int o = 32; o > 0; o >>= 1) p += __shfl_xor(p, o);
        if (lane == 0) red[it & 1][wid] = p;
        __syncthreads();
        float S = 0.0f;
        for (int w = 0; w < 16; w++) S += red[it & 1][w];
        a = cst - M - 0.1f * logf(S);
    }
    int p = 0, c1 = 0;
#pragma unroll
    for (int i = 0; i < 8; i++) {
        float sc = expf(fminf(sv[i] + a, 0.0f) * 10.0f);
        int n = tid + 1024 * i;
        keys[b * NSEQ + n] = ((unsigned long long)__float_as_uint(sc) << 32)
                           | (unsigned long long)(0xFFFFFFFFu - (unsigned)n);
        p  += (sc > 0.0f) ? 1 : 0;
        c1 += (sc == 1.0f) ? 1 : 0;
    }
#pragma unroll
    for (int o = 32; o > 0; o >>= 1) {
        p  += __shfl_xor(p, o);
        c1 += __shfl_xor(c1, o);
    }
    if (lane == 0) { atomicAdd(&pcount[b], p); atomicAdd(&c1cnt[b], c1); }
}

__global__ __launch_bounds__(1024) void k_select(const unsigned long long* __restrict__ keys,
                                                 const int* __restrict__ pcount,
                                                 const int* __restrict__ c1cnt,
                                                 int* __restrict__ rowmap) {
    int b = blockIdx.x, tid = threadIdx.x;
    int lane = tid & 63, wid = tid >> 6;
    __shared__ int wsum[16];
    __shared__ int slot;
    __shared__ unsigned long long kk_[NSEQ];
    int P = pcount[b], C1 = c1cnt[b];
    if (C1 >= NHEAVY) {
        bool f[8]; int zc = 0;
#pragma unroll
        for (int j = 0; j < 8; j++) {
            unsigned hi = (unsigned)(keys[b * NSEQ + tid * 8 + j] >> 32);
            f[j] = (hi == 0x3F800000u);
            zc += f[j] ? 1 : 0;
        }
        int inc = zc;
        for (int o = 1; o < 64; o <<= 1) {
            int t = __shfl_up(inc, o);
            if (lane >= o) inc += t;
        }
        if (lane == 63) wsum[wid] = inc;
        __syncthreads();
        if (tid == 0) {
            int acc = 0;
            for (int w = 0; w < 16; w++) { int t = wsum[w]; wsum[w] = acc; acc += t; }
        }
        __syncthreads();
        int rank = wsum[wid] + (inc - zc);
#pragma unroll
        for (int j = 0; j < 8; j++) {
            if (f[j]) {
                if (rank < NHEAVY) rowmap[b * NHEAVY + rank] = b * NSEQ + tid * 8 + j;
                rank++;
            }
        }
    } else if (P <= NHEAVY) {
        bool pos[8]; int zc = 0;
#pragma unroll
        for (int j = 0; j < 8; j++) {
            unsigned sbits = (unsigned)(keys[b * NSEQ + tid * 8 + j] >> 32);
            pos[j] = (sbits != 0u);
            zc += pos[j] ? 0 : 1;
        }
        int inc = zc;
        for (int o = 1; o < 64; o <<= 1) {
            int t = __shfl_up(inc, o);
            if (lane >= o) inc += t;
        }
        if (lane == 63) wsum[wid] = inc;
        if (tid == 0) slot = 0;
        __syncthreads();
        if (tid == 0) {
            int acc = 0;
            for (int w = 0; w < 16; w++) { int t = wsum[w]; wsum[w] = acc; acc += t; }
        }
        __syncthreads();
        int zr = wsum[wid] + (inc - zc);
        int Z = NHEAVY - P;
#pragma unroll
        for (int j = 0; j < 8; j++) {
            int n = tid * 8 + j;
            bool sel;
            if (pos[j]) sel = true;
            else { sel = (zr < Z); zr += 1; }
            if (sel) {
                int sl = atomicAdd(&slot, 1);
                rowmap[b * NHEAVY + sl] = b * NSEQ + n;
            }
        }
    } else {
        for (int i = tid; i < NSEQ; i += 1024) kk_[i] = keys[b * NSEQ + i];
        __syncthreads();
        for (int k = 2; k <= NSEQ; k <<= 1) {
            for (int j = k >> 1; j > 0; j >>= 1) {
                for (int i = tid; i < NSEQ; i += 1024) {
                    int ixj = i ^ j;
                    if (ixj > i) {
                        unsigned long long u = kk_[i], v = kk_[ixj];
                        bool dirDesc = ((i & k) == 0);
                        if (dirDesc ? (u < v) : (u > v)) { kk_[i] = v; kk_[ixj] = u; }
                    }
                }
                __syncthreads();
            }
        }
        unsigned idx = 0xFFFFFFFFu - (unsigned)(kk_[tid] & 0xFFFFFFFFull);
        rowmap[b * NHEAVY + tid] = b * NSEQ + (int)idx;
    }
}

__global__ __launch_bounds__(256) void k_transpose(const float* __restrict__ W,
                                                   unsigned short* __restrict__ WT,
                                                   int K, int N) {
    transpose_body(W, WT, K, N, blockIdx.x * 64, blockIdx.y * 64, nullptr);
}

// ---- prescale (fallback path) ----
__global__ __launch_bounds__(256) void k_prescale(const float* __restrict__ x,
                                                  const float* __restrict__ invr,
                                                  const float* __restrict__ gamma,
                                                  const int* __restrict__ rowmap,
                                                  unsigned short* __restrict__ xo,
                                                  int row_ofs) {
    int t = threadIdx.x;
    int i = blockIdx.x * 2 + (t >> 7);
    int c = (t & 127) * 8;
    int src = rowmap ? rowmap[i] : (row_ofs + i);
    float iv = invr[src];
    const float4* px = (const float4*)(x + (size_t)src * DIMD + c);
    const float4* pg = (const float4*)(gamma + c);
    float4 v0 = px[0], v1 = px[1];
    float4 g0 = pg[0], g1 = pg[1];
    unsigned short o[8];
    o[0] = bf16rne(v0.x * iv * g0.x); o[1] = bf16rne(v0.y * iv * g0.y);
    o[2] = bf16rne(v0.z * iv * g0.z); o[3] = bf16rne(v0.w * iv * g0.w);
    o[4] = bf16rne(v1.x * iv * g1.x); o[5] = bf16rne(v1.y * iv * g1.y);
    o[6] = bf16rne(v1.z * iv * g1.z); o[7] = bf16rne(v1.w * iv * g1.w);
    *(u16x8*)(xo + (size_t)i * DIMD + c) = *(u16x8*)o;
}

// ---- scatter-add: out[rowmap[i]][*] += rb[i][*]  (rows unique, no atomics) ----
__global__ __launch_bounds__(256) void k_scatter(const float* __restrict__ rb,
                                                 const int* __restrict__ rowmap,
                                                 float* __restrict__ out) {
    int i = blockIdx.x;
    int c = threadIdx.x * 4;
    int g = rowmap[i];
    float4 v = *(const float4*)(rb + (size_t)i * DIMD + c);
    float* p = out + (size_t)g * DIMD + c;
    float4 o = *(const float4*)p;
    o.x += v.x; o.y += v.y; o.z += v.z; o.w += v.w;
    *(float4*)p = o;
}

// ---- 128x128 bf16 MFMA GEMM body (R9-proven loop; VGPR 64, 0 conflicts) ----
// EPI 0: bf16 gelu(acc+bias)
// EPI 1: f32 C[m_ofs+row] = acc+bias
// EPI 2: f32 C[rowmap[m_ofs+row]] += acc+bias      [fallback heavy-G2]
// EPI 5: bf16 gelu(acc*invr[row]+bias)             [light-G1]
// EPI 6: GATHER A via rowmap; bf16 gelu(acc*invr[rowmap[row]]+bias)  [heavy-G1]
struct GArg {
    const unsigned short* A; const unsigned short* BT; const float* bias;
    void* C; const int* rowmap; const float* invr;
    int K, kslice, m_ofs, ldc, nx, ny;
};

template<int EPI>
__device__ __forceinline__ void gemm_body(const GArg ga, int w, int nwg,
                                          unsigned short* As, unsigned short* Bs) {
    int tid = threadIdx.x;
    int q = nwg >> 3, r = nwg & 7;
    int xcd = w & 7, sub = w >> 3;
    int id = (xcd < r ? xcd * (q + 1) : r * (q + 1) + (xcd - r) * q) + sub;
    int bx = id % ga.nx;
    int t2 = id / ga.nx;
    int by = t2 % ga.ny;
    int bz = t2 / ga.ny;
    (void)bz;

    int m0 = by * 128, n0 = bx * 128;
    int kbeg = bz * ga.kslice, kend = kbeg + ga.kslice;
    int K = ga.K;
    int lane = tid & 63, wid = tid >> 6;
    int wm = wid >> 1, wn = wid & 1;
    int lc = lane & 15, lr = lane >> 4;

    int srow = lane >> 3;
    int sslot = (lane & 7) ^ srow;
    const unsigned short* paB = ga.BT + (size_t)(n0 + srow) * K + sslot * 8;
    const unsigned short* paA;
    int growq[4];
    if constexpr (EPI == 6) {
#pragma unroll
        for (int qq = 0; qq < 4; qq++)
            growq[qq] = ga.rowmap[m0 + (wid * 4 + qq) * 8 + srow];
        paA = ga.A + sslot * 8;
    } else {
        paA = ga.A + (size_t)(m0 + srow) * K + sslot * 8;
    }

    f32x4 acc[4][4];
#pragma unroll
    for (int i = 0; i < 4; i++)
#pragma unroll
        for (int j = 0; j < 4; j++) acc[i][j] = (f32x4){0.f, 0.f, 0.f, 0.f};

    for (int k0 = kbeg; k0 < kend; k0 += 64) {
        if (k0 != kbeg) __syncthreads();
#pragma unroll
        for (int qq = 0; qq < 4; qq++) {
            int rb_ = (wid * 4 + qq) * 8;
            if constexpr (EPI == 6)
                gload_lds16(paA + (size_t)growq[qq] * K + k0, &As[rb_ * 64]);
            else
                gload_lds16(paA + (size_t)rb_ * K + k0, &As[rb_ * 64]);
            gload_lds16(paB + (size_t)rb_ * K + k0, &Bs[rb_ * 64]);
        }
        __syncthreads();
#pragma unroll
        for (int ks = 0; ks < 2; ks++) {
            bf16x8 af[4], bfr[4];
#pragma unroll
            for (int f = 0; f < 4; f++) {
                int rowA = wm * 64 + f * 16 + lc;
                int rowB = wn * 64 + f * 16 + lc;
                int sw = ((ks * 4 + lr) ^ (lc & 7)) << 4;
                af[f]  = *(const bf16x8*)((const char*)As + rowA * 128 + sw);
                bfr[f] = *(const bf16x8*)((const char*)Bs + rowB * 128 + sw);
            }
#pragma unroll
            for (int fm = 0; fm < 4; fm++)
#pragma unroll
                for (int fn = 0; fn < 4; fn++)
                    acc[fm][fn] = __builtin_amdgcn_mfma_f32_16x16x32_bf16(
                        af[fm], bfr[fn], acc[fm][fn], 0, 0, 0);
        }
    }

    float bcol[4];
#pragma unroll
    for (int fn = 0; fn < 4; fn++) bcol[fn] = ga.bias[n0 + wn * 64 + fn * 16 + lc];
#pragma unroll
    for (int fm = 0; fm < 4; fm++) {
        int rowb = m0 + wm * 64 + fm * 16 + lr * 4;
#pragma unroll
        for (int fn = 0; fn < 4; fn++) {
            int col = n0 + wn * 64 + fn * 16 + lc;
            f32x4 v = acc[fm][fn];
#pragma unroll
            for (int rr = 0; rr < 4; rr++) {
                if constexpr (EPI == 0) {
                    float val = v[rr] + bcol[fn];
                    ((unsigned short*)ga.C)[(size_t)(rowb + rr) * ga.ldc + col] =
                        bf16rne(gelu_f(val));
                } else if constexpr (EPI == 1) {
                    ((float*)ga.C)[(size_t)(ga.m_ofs + rowb + rr) * ga.ldc + col] =
                        v[rr] + bcol[fn];
                } else if constexpr (EPI == 2) {
                    int g = ga.rowmap[ga.m_ofs + rowb + rr];
                    float* p = (float*)ga.C + (size_t)g * ga.ldc + col;
                    *p = *p + v[rr] + bcol[fn];
                } else if constexpr (EPI == 5) {
                    float val = v[rr] * ga.invr[rowb + rr] + bcol[fn];
                    ((unsigned short*)ga.C)[(size_t)(rowb + rr) * ga.ldc + col] =
                        bf16rne(gelu_f(val));
                } else {  // EPI == 6
                    int g = ga.rowmap[rowb + rr];
                    float val = v[rr] * ga.invr[g] + bcol[fn];
                    ((unsigned short*)ga.C)[(size_t)(rowb + rr) * ga.ldc + col] =
                        bf16rne(gelu_f(val));
                }
            }
        }
    }
}

// (256,4) is the measured optimum for this body: VGPR 64, no spill.
// (256,5) twice measured to squeeze VGPR -> scratch spill (R10, R15). Do not raise.
// Heavy-G2 split-K w/ atomics measured -42 us (R17). Keep unsplit heavy-first.
template<int EPI>
__global__ __launch_bounds__(256, 4) void k_mfma(GArg ga) {
    __shared__ unsigned short sm[2][128 * 64];
    gemm_body<EPI>(ga, (int)blockIdx.x, (int)gridDim.x, sm[0], sm[1]);
}

template<int EA, int EB>
__global__ __launch_bounds__(256, 4) void k_mfma2(GArg a, GArg b, int nwgA) {
    __shared__ unsigned short sm[2][128 * 64];
    int w = (int)blockIdx.x;
    if (w < nwgA) gemm_body<EA>(a, w, nwgA, sm[0], sm[1]);
    else          gemm_body<EB>(b, w - nwgA, (int)gridDim.x - nwgA, sm[0], sm[1]);
}

extern "C" void kernel_launch(void* const* d_in, const int* in_sizes, int n_in,
                              void* d_out, int out_size, void* d_ws, size_t ws_size,
                              hipStream_t stream) {
    const float* x   = (const float*)d_in[0];
    const float* rt  = (const float*)d_in[1];
    const float* gl  = (const float*)d_in[2];
    const float* w1l = (const float*)d_in[3];
    const float* b1l = (const float*)d_in[4];
    const float* w2l = (const float*)d_in[5];
    const float* b2l = (const float*)d_in[6];
    const float* gh  = (const float*)d_in[7];
    const float* w1h = (const float*)d_in[8];
    const float* b1h = (const float*)d_in[9];
    const float* w2h = (const float*)d_in[10];
    const float* b2h = (const float*)d_in[11];
    float* out = (float*)d_out;

    char* ws = (char*)d_ws;
    float* s    = (float*)(ws);
    float* invr = (float*)(ws + 131072);
    unsigned long long* keys = (unsigned long long*)(ws + 262144);
    int* rowmap = (int*)(ws + 524288);
    int* pcount = (int*)(ws + 540672);
    int* c1cnt  = pcount + 4;
    size_t off = 1u << 20;
    unsigned short* w1lT = (unsigned short*)(ws + off); off += (size_t)LHID * DIMD * 2;
    unsigned short* w2lT = (unsigned short*)(ws + off); off += (size_t)DIMD * LHID * 2;
    unsigned short* w1hT = (unsigned short*)(ws + off); off += (size_t)HHID * DIMD * 2;
    unsigned short* w2hT = (unsigned short*)(ws + off); off += (size_t)DIMD * HHID * 2;
    unsigned short* xhg  = (unsigned short*)(ws + off); off += (size_t)BATCH * NHEAVY * DIMD * 2;
    char* un = ws + off;
    size_t U = ws_size > off ? ws_size - off : 0;

    const size_t XL_B = (size_t)TOKS * DIMD * 2;           // 64 MiB
    const size_t HL_B = (size_t)TOKS * LHID * 2;           // 32 MiB
    const size_t HH_B = (size_t)BATCH * NHEAVY * HHID * 2; // 32 MiB
    bool big = (U >= XL_B + HL_B + HH_B);

    const long MH = (long)BATCH * NHEAVY;   // 4096

    if (big) {
        unsigned short* xc = (unsigned short*)un;
        unsigned short* hl = (unsigned short*)(un + XL_B);
        unsigned short* hh = (unsigned short*)(un + XL_B + HL_B);
        float* rb = (float*)un;                            // aliases xc (dead after G1)

        // D1: xcast (s, invr, xc) || all 4 weight transposes (gamma folded into w1*)
        k_pre<<<8192 + 2304, 256, 0, stream>>>(x, rt, gl, gh,
                                               w1l, w1lT, w2l, w2lT,
                                               w1h, w1hT, w2h, w2hT,
                                               s, invr, xc);
        // D2: routing + selection
        k_routesel<<<BATCH, 1024, 0, stream>>>(s, rowmap);

        // D3 MEGA-G1: heavy-G1 gather (1024) || light-G1 (1024), both K=1024
        GArg hg1{xc, w1hT, b1h, hh, rowmap, invr, DIMD, DIMD, 0, HHID, HHID / 128, (int)MH / 128};
        GArg lg1{xc, w1lT, b1l, hl, nullptr, invr, DIMD, DIMD, 0, LHID, LHID / 128, TOKS / 128};
        k_mfma2<6, 5><<<2048, 256, 0, stream>>>(hg1, lg1, 1024);

        // D4 MEGA-G2: heavy-G2 (256, K=4096) -> rb || light-G2 (2048, K=512) -> out
        GArg hg2{hh, w2hT, b2h, rb,  nullptr, nullptr, HHID, HHID, 0, DIMD, DIMD / 128, (int)MH / 128};
        GArg lg2{hl, w2lT, b2l, out, nullptr, nullptr, LHID, LHID, 0, DIMD, DIMD / 128, TOKS / 128};
        k_mfma2<1, 1><<<2304, 256, 0, stream>>>(hg2, lg2, 256);

        // D5: scatter heavy rows into out
        k_scatter<<<(unsigned)MH, 256, 0, stream>>>(rb, rowmap, out);
    } else {
        // fallback: chunked path (small workspace)
        hipMemsetAsync(pcount, 0, 32, stream);
        k_rowstats<<<TOKS / 4, 256, 0, stream>>>(x, rt, s, invr);
        k_route<<<BATCH, 1024, 0, stream>>>(s, keys, pcount, c1cnt);
        k_select<<<BATCH, 1024, 0, stream>>>(keys, pcount, c1cnt, rowmap);

        k_transpose<<<dim3(LHID / 64, DIMD / 64), 256, 0, stream>>>(w1l, w1lT, DIMD, LHID);
        k_transpose<<<dim3(DIMD / 64, LHID / 64), 256, 0, stream>>>(w2l, w2lT, LHID, DIMD);
        k_transpose<<<dim3(HHID / 64, DIMD / 64), 256, 0, stream>>>(w1h, w1hT, DIMD, HHID);
        k_transpose<<<dim3(DIMD / 64, HHID / 64), 256, 0, stream>>>(w2h, w2hT, HHID, DIMD);

        long Rl = (long)(U / 3072);
        Rl -= Rl % 128; if (Rl < 128) Rl = 128; if (Rl > TOKS) Rl = TOKS;
        unsigned short* xl = (unsigned short*)un;
        unsigned short* hl = (unsigned short*)(un + (size_t)Rl * DIMD * 2);
        for (long mo = 0; mo < TOKS; mo += Rl) {
            long R = TOKS - mo < Rl ? TOKS - mo : Rl;
            k_prescale<<<(unsigned)(R / 2), 256, 0, stream>>>(x, invr, gl, nullptr, xl, (int)mo);
            GArg a1{xl, w1lT, b1l, hl, nullptr, nullptr, DIMD, DIMD, 0, LHID, LHID / 128, (int)(R / 128)};
            k_mfma<0><<<(LHID / 128) * (unsigned)(R / 128), 256, 0, stream>>>(a1);
            GArg a2{hl, w2lT, b2l, out, nullptr, nullptr, LHID, LHID, (int)mo, DIMD, DIMD / 128, (int)(R / 128)};
            k_mfma<1><<<(DIMD / 128) * (unsigned)(R / 128), 256, 0, stream>>>(a2);
        }

        k_prescale<<<(unsigned)(MH / 2), 256, 0, stream>>>(x, invr, gh, rowmap, xhg, 0);
        long Rh = (long)(U / ((size_t)HHID * 2));
        Rh -= Rh % 128; if (Rh < 128) Rh = 128; if (Rh > MH) Rh = MH;
        unsigned short* hh = (unsigned short*)un;
        for (long mo = 0; mo < MH; mo += Rh) {
            long R = MH - mo < Rh ? MH - mo : Rh;
            GArg b1{xhg + (size_t)mo * DIMD, w1hT, b1h, hh, nullptr, nullptr, DIMD, DIMD, 0, HHID,
                    HHID / 128, (int)(R / 128)};
            k_mfma<0><<<(HHID / 128) * (unsigned)(R / 128), 256, 0, stream>>>(b1);
            GArg b2{hh, w2hT, b2h, out, rowmap, nullptr, HHID, HHID, (int)mo, DIMD,
                    DIMD / 128, (int)(R / 128)};
            k_mfma<2><<<(DIMD / 128) * (unsigned)(R / 128), 256, 0, stream>>>(b2);
        }
    }
}